// Round 19
// baseline (43.738 us; speedup 1.0000x reference)
//
#include <hip/hip_runtime.h>
#include <hip/hip_bf16.h>

// Problem dims (fixed)
#define BB   8
#define LL   32
#define NINV 64
#define NOUTV 16
#define DINV 128
#define EE   64
#define DCV  512

#define EPSF 1e-8f
#define LBDF 1e-3f
// 32 * ln(2*pi)
#define SUM_LN2PI 58.8120661250990508f

// f16 MFMA scaling: A(u) x 2^12, B(sc*Wv) x 2^10, descale 2^-22
#define SA_F 4096.0f
#define SB_F 1024.0f
#define DESCALE (1.0f / 4194304.0f)

typedef float f32x4v __attribute__((ext_vector_type(4)));
typedef _Float16 f16x8 __attribute__((ext_vector_type(8)));
typedef __fp16 fp16x2 __attribute__((ext_vector_type(2)));

union pk16 { fp16x2 h; unsigned int u; };

static __device__ __forceinline__ unsigned int cvt_pk_bf16(float lo, float hi) {
    unsigned int r;
    asm("v_cvt_pk_bf16_f32 %0, %1, %2" : "=v"(r) : "v"(lo), "v"(hi));
    return r;
}

// ---------------------------------------------------------------------------
// Kernel 1 (merged front-end), 1288 blocks x 256 threads.
// R19 change (priors branch only): GEMM1 d-split de-duplication. The R14-R18
// form had all 4 bg-groups loading the SAME rw dwords (4x redundant issue,
// 134 MB load traffic vs the 33.5 MB tile). Now: inu staged TRANSPOSED
// (inu_t[d][b], stride 10), thread (bg,e) owns d in [bg*32,bg*32+32) and
// accumulates all 8 b's -> rw read exactly once; per-wave: 32 global loads
// (was 128), 128 ds_read (was 256), fma unchanged. Partials [4][8][64]
// reduced in one LDS pass; GEMM2 unchanged.
// ---------------------------------------------------------------------------
__global__ __launch_bounds__(256) void pre_kernel(
    const float* __restrict__ inu, const float* __restrict__ rw,
    const float* __restrict__ Wu, const float* __restrict__ bu,
    const float* __restrict__ ctx, const float* __restrict__ Wc, const float* __restrict__ bc,
    const float* __restrict__ Wv, const float* __restrict__ bv,
    const float* __restrict__ Wa, const float* __restrict__ ba,
    _Float16* __restrict__ u16, _Float16* __restrict__ scwv,
    float* __restrict__ vbar_out, float* __restrict__ actn_out)
{
    const int blk = blockIdx.x;
    const int tid = threadIdx.x;
    // priors: [0,1280) inu_t | [1280,3328) partials | [3328,3840) pri
    // prep-c: [0,768) ctx row + c-partials | [768,832) tanh(c)
    __shared__ float smem[3840];

    if (blk < NINV * NOUTV) {
        // ---------------- priors + u (f16) ----------------
        const int n = blk >> 4;
        {   // stage inu[:, n, :] transposed: inu_t[d*10 + b]
            const int b = tid >> 5;
            const int d0 = (tid & 31) * 4;
            const float4 s = *(const float4*)(inu + ((size_t)b * NINV + n) * DINV + d0);
            smem[(d0 + 0) * 10 + b] = s.x;
            smem[(d0 + 1) * 10 + b] = s.y;
            smem[(d0 + 2) * 10 + b] = s.z;
            smem[(d0 + 3) * 10 + b] = s.w;
        }
        __syncthreads();

        {   // GEMM1: thread (bg = tid>>6, e = tid&63); d in [bg*32, bg*32+32)
            const int bg = tid >> 6;
            const int e = tid & 63;
            const float* rwp = rw + (size_t)blk * DINV * EE + e + (size_t)(bg * 32) * EE;
            float pa0 = 0.f, pa1 = 0.f, pa2 = 0.f, pa3 = 0.f;
            float pa4 = 0.f, pa5 = 0.f, pa6 = 0.f, pa7 = 0.f;
            const float* it = &smem[(bg * 32) * 10];
            #pragma unroll 8
            for (int dd = 0; dd < 32; ++dd) {
                const float w = rwp[dd * EE];
                const float2 i01 = *(const float2*)&it[dd * 10 + 0];
                const float2 i23 = *(const float2*)&it[dd * 10 + 2];
                const float2 i45 = *(const float2*)&it[dd * 10 + 4];
                const float2 i67 = *(const float2*)&it[dd * 10 + 6];
                pa0 = fmaf(i01.x, w, pa0);  pa1 = fmaf(i01.y, w, pa1);
                pa2 = fmaf(i23.x, w, pa2);  pa3 = fmaf(i23.y, w, pa3);
                pa4 = fmaf(i45.x, w, pa4);  pa5 = fmaf(i45.y, w, pa5);
                pa6 = fmaf(i67.x, w, pa6);  pa7 = fmaf(i67.y, w, pa7);
            }
            float* pp = &smem[1280 + bg * 512 + e];
            pp[0 * 64] = pa0;  pp[1 * 64] = pa1;  pp[2 * 64] = pa2;  pp[3 * 64] = pa3;
            pp[4 * 64] = pa4;  pp[5 * 64] = pa5;  pp[6 * 64] = pa6;  pp[7 * 64] = pa7;
        }
        __syncthreads();

        {   // combine partials -> pri[b*64+e] at smem+3328 (256 thr x 2)
            const int i0 = tid * 2;
            const float2 a = *(const float2*)&smem[1280 + i0];
            const float2 b2 = *(const float2*)&smem[1280 + 512 + i0];
            const float2 c = *(const float2*)&smem[1280 + 1024 + i0];
            const float2 d = *(const float2*)&smem[1280 + 1536 + i0];
            *(float2*)&smem[3328 + i0] =
                make_float2(a.x + b2.x + c.x + d.x, a.y + b2.y + c.y + d.y);
        }
        __syncthreads();

        // GEMM2: thread (bq, e-pair); u -> f16 x 2^12, coalesced dwords
        const int bq = tid >> 5;
        const int e0 = (tid & 31) * 2;
        float b0 = bu[e0], b1 = bu[e0 + 1];
        const float* p = &smem[3328 + bq * EE];
        for (int e1 = 0; e1 < EE; ++e1) {
            const float2 w = *(const float2*)&Wu[e1 * EE + e0];
            b0 = fmaf(p[e1], w.x, b0);
            b1 = fmaf(p[e1], w.y, b1);
        }
        pk16 pk;
        pk.h = __builtin_amdgcn_cvt_pkrtz(b0 * SA_F, b1 * SA_F);
        *(unsigned int*)((char*)u16 + (((size_t)bq * 1024 + blk) * EE + e0) * 2) = pk.u;

    } else if (blk < NINV * NOUTV + BB * LL) {
        // ---------------- prep-c: c, vbar, scWv ----------------
        const int bl = blk - NINV * NOUTV;
        const float* cr = ctx + (size_t)bl * DCV;
        smem[tid] = cr[tid];
        smem[tid + 256] = cr[tid + 256];
        __syncthreads();
        {
            const int q = tid >> 6;
            const int e = tid & 63;
            const float* rp = smem + q * 128;
            const float* wp = Wc + (q * 128) * EE + e;
            float acc = 0.0f;
            for (int d = 0; d < 128; ++d) acc = fmaf(rp[d], wp[d * EE], acc);
            __syncthreads();          // row data no longer needed
            smem[512 + q * 64 + e] = acc;
        }
        __syncthreads();
        if (tid < EE) {
            const float c = smem[512 + tid] + smem[576 + tid] + smem[640 + tid]
                          + smem[704 + tid] + bc[tid];
            smem[768 + tid] = tanhf(c);
        }
        __syncthreads();
        if (tid < EE) {
            const int t = tid;
            float vb = bv[t];
            pk16 scw[32];
            #pragma unroll
            for (int e2 = 0; e2 < 32; ++e2) {
                const float t0 = smem[768 + 2 * e2], t1 = smem[768 + 2 * e2 + 1];
                const float w0 = Wv[(2 * e2) * EE + t];
                const float w1 = Wv[(2 * e2 + 1) * EE + t];
                vb = fmaf(t0, w0, fmaf(t1, w1, vb));
                const float s0 = fmaf(-t0, t0, 1.0f) * w0 * SB_F;
                const float s1 = fmaf(-t1, t1, 1.0f) * w1 * SB_F;
                scw[e2].h = __builtin_amdgcn_cvt_pkrtz(s0, s1);
            }
            vbar_out[bl * EE + t] = vb;
            uint4* dst = (uint4*)((char*)scwv + ((size_t)bl * EE + t) * EE * 2);
            #pragma unroll
            for (int q = 0; q < 8; ++q) {
                uint4 v;
                v.x = scw[q * 4 + 0].u;
                v.y = scw[q * 4 + 1].u;
                v.z = scw[q * 4 + 2].u;
                v.w = scw[q * 4 + 3].u;
                dst[q] = v;
            }
        }
    } else {
        // ---------------- actn ----------------
        const int b = blk - (NINV * NOUTV + BB * LL);
        if (tid < NINV) {
            const float* ir = inu + ((size_t)b * NINV + tid) * DINV;
            float acc = ba[0];
            for (int d = 0; d < DINV; ++d) acc = fmaf(ir[d], Wa[d], acc);
            actn_out[b * NINV + tid] = 1.0f / (1.0f + expf(-acc));
        }
    }
}

// ---------------------------------------------------------------------------
// Kernel 2 (fused): one 1024-thread block per (b,l).  (verbatim R18)
// Phase A: dv via mfma(scwv_frag, u_frag) (swap verified R17) -> b64 stores.
// Phase B: EM, wave-per-o m-pass (R16 form, proven).
// ---------------------------------------------------------------------------
__global__ __launch_bounds__(1024) void em_fused_kernel(
    const _Float16* __restrict__ u16, const _Float16* __restrict__ scwv,
    const float* __restrict__ vbar_all, const float* __restrict__ actn_all,
    const unsigned char* __restrict__ mask_all,
    const float* __restrict__ beta_u, const float* __restrict__ beta_a,
    float* __restrict__ out_mu, float* __restrict__ out_r)
{
    const int bl = blockIdx.x;           // 0..255  (= b*32 + l)
    const int b = bl >> 5;
    const int tid = threadIdx.x;
    const int n = tid >> 4;              // e-step role
    const int o = tid & 15;
    const int wid = tid >> 6;            // wave 0..15
    const int lane = tid & 63;
    const int l15 = lane & 15;
    const int lk = (lane >> 4) * 8;      // k-offset of this lane's A/B elems

    __shared__ __align__(16) unsigned int dv_sh[NINV * NOUTV * (EE / 2)]; // 128 KB
    __shared__ __align__(16) float dmu_sh[NOUTV][68];
    __shared__ __align__(16) float q_sh[NOUTV][68];
    __shared__ __align__(16) float ar_t[NOUTV][68];     // transposed: [o][n]
    __shared__ float actn_sh[NINV];
    __shared__ float vbar_sh[EE];
    __shared__ float sumhl_sh[NOUTV];
    __shared__ float logact_sh[NOUTV];

    char* dvb = (char*)dv_sh;

    if (tid < NINV) actn_sh[tid] = actn_all[b * NINV + tid];
    else if (tid < NINV + EE) vbar_sh[tid - NINV] = vbar_all[bl * EE + (tid - NINV)];

    // ---- scwv fragments (A-operand after swap): row = e_out = ct*16+l15 ----
    f16x8 bfr[4][2];
    #pragma unroll
    for (int ct = 0; ct < 4; ++ct) {
        #pragma unroll
        for (int kh = 0; kh < 2; ++kh) {
            bfr[ct][kh] = *(const f16x8*)((const char*)scwv +
                (((size_t)bl * EE + (ct * 16 + l15)) * EE + kh * 32 + lk) * 2);
        }
    }

    // ---- Phase A: dv via mfma(scwv, u) -> b64 swizzled stores ----
    {
        const char* urow = (const char*)u16 +
            ((size_t)b * 1024 + wid * 64 + l15) * EE * 2;
        #pragma unroll
        for (int rt = 0; rt < 4; ++rt) {
            const char* up = urow + (size_t)rt * 16 * EE * 2;
            const f16x8 a0 = *(const f16x8*)(up + lk * 2);
            const f16x8 a1 = *(const f16x8*)(up + 64 + lk * 2);
            const int row = wid * 64 + rt * 16 + l15;      // dv row (u-row)
            const int rsw = (row & 7);
            #pragma unroll
            for (int ct = 0; ct < 4; ++ct) {
                f32x4v acc = {0.0f, 0.0f, 0.0f, 0.0f};
                acc = __builtin_amdgcn_mfma_f32_16x16x32_f16(bfr[ct][0], a0, acc, 0, 0, 0);
                acc = __builtin_amdgcn_mfma_f32_16x16x32_f16(bfr[ct][1], a1, acc, 0, 0, 0);
                const int e0c = ct * 16 + (lane >> 4) * 4; // 4 consecutive e's
                const int kc = e0c >> 3;
                uint2 pk2;
                pk2.x = cvt_pk_bf16(acc[0] * DESCALE, acc[1] * DESCALE);
                pk2.y = cvt_pk_bf16(acc[2] * DESCALE, acc[3] * DESCALE);
                *(uint2*)(dvb + row * 128 + ((kc ^ rsw) << 4) + ((e0c & 7) << 1)) = pk2;
            }
        }
    }
    __syncthreads();                                   // dv + staging ready

    const unsigned char msk = mask_all[b * NINV + n];
    float r_loc = 1.0f / 16.0f;

    // m-pass lane roles (one o per wave)
    const int o_m = wid;
    const int eq = lane & 15;            // e-quad: e0 = eq*4
    const int qn = lane >> 4;            // n-quarter
    const int e0m = eq * 4;
    const char* dvp = dvb + qn * 32768 + o_m * 128
                    + (((eq >> 1) ^ (o_m & 7)) << 4) + ((eq & 1) << 3);
    const float4* ar4 = (const float4*)&ar_t[o_m][qn * 16];

    for (int it = 0; it < 3; ++it) {
        // ---- ar (normalized over o), write transposed to LDS ----
        float arv = actn_sh[n] * r_loc;
        float s = arv;
        s += __shfl_xor(s, 1, 64);
        s += __shfl_xor(s, 2, 64);
        s += __shfl_xor(s, 4, 64);
        s += __shfl_xor(s, 8, 64);
        arv = arv / (s + EPSF);
        ar_t[o][n] = arv;
        __syncthreads();                               // B1

        if (it < 2) {
            // ---- m-pass: all 16 waves; wave o_m; lane (qn, eq) ----
            float S10 = 0.0f, S11 = 0.0f, S12 = 0.0f, S13 = 0.0f;
            float S20 = 0.0f, S21 = 0.0f, S22 = 0.0f, S23 = 0.0f;
            float A = 0.0f;
            #pragma unroll
            for (int g = 0; g < 4; ++g) {
                const float4 ag = ar4[g];
                #pragma unroll
                for (int i2 = 0; i2 < 4; ++i2) {
                    const float av = (i2 == 0) ? ag.x : (i2 == 1) ? ag.y
                                   : (i2 == 2) ? ag.z : ag.w;
                    const uint2 w2 = *(const uint2*)(dvp + (g * 4 + i2) * 2048);
                    const float v0 = __uint_as_float(w2.x << 16);
                    const float v1 = __uint_as_float(w2.x & 0xFFFF0000u);
                    const float v2 = __uint_as_float(w2.y << 16);
                    const float v3 = __uint_as_float(w2.y & 0xFFFF0000u);
                    A += av;
                    S10 = fmaf(av, v0, S10);  S20 = fmaf(av * v0, v0, S20);
                    S11 = fmaf(av, v1, S11);  S21 = fmaf(av * v1, v1, S21);
                    S12 = fmaf(av, v2, S12);  S22 = fmaf(av * v2, v2, S22);
                    S13 = fmaf(av, v3, S13);  S23 = fmaf(av * v3, v3, S23);
                }
            }
            S10 += __shfl_xor(S10, 16, 64); S10 += __shfl_xor(S10, 32, 64);
            S11 += __shfl_xor(S11, 16, 64); S11 += __shfl_xor(S11, 32, 64);
            S12 += __shfl_xor(S12, 16, 64); S12 += __shfl_xor(S12, 32, 64);
            S13 += __shfl_xor(S13, 16, 64); S13 += __shfl_xor(S13, 32, 64);
            S20 += __shfl_xor(S20, 16, 64); S20 += __shfl_xor(S20, 32, 64);
            S21 += __shfl_xor(S21, 16, 64); S21 += __shfl_xor(S21, 32, 64);
            S22 += __shfl_xor(S22, 16, 64); S22 += __shfl_xor(S22, 32, 64);
            S23 += __shfl_xor(S23, 16, 64); S23 += __shfl_xor(S23, 32, 64);
            A   += __shfl_xor(A, 16, 64);   A   += __shfl_xor(A, 32, 64);

            const float iD = 1.0f / (A + EPSF);
            const float m0 = S10 * iD, m1 = S11 * iD, m2 = S12 * iD, m3 = S13 * iD;
            const float sa0 = fmaxf(fmaf(-m0, m0, S20 * iD), 0.0f) + EPSF;
            const float sa1 = fmaxf(fmaf(-m1, m1, S21 * iD), 0.0f) + EPSF;
            const float sa2 = fmaxf(fmaf(-m2, m2, S22 * iD), 0.0f) + EPSF;
            const float sa3 = fmaxf(fmaf(-m3, m3, S23 * iD), 0.0f) + EPSF;
            if (qn == 0) {
                *(float4*)&dmu_sh[o_m][e0m] = make_float4(m0, m1, m2, m3);
                *(float4*)&q_sh[o_m][e0m] =
                    make_float4(0.5f / sa0, 0.5f / sa1, 0.5f / sa2, 0.5f / sa3);
            }
            float hl = 0.5f * (logf(sa0) + logf(sa1) + logf(sa2) + logf(sa3));
            hl += __shfl_xor(hl, 1, 64);
            hl += __shfl_xor(hl, 2, 64);
            hl += __shfl_xor(hl, 4, 64);
            hl += __shfl_xor(hl, 8, 64);
            if (lane == 0) {
                sumhl_sh[o_m] = hl;
                const float cost = 64.0f * beta_u[o_m] + A * hl;
                const float x = LBDF * (beta_a[o_m] - cost);
                logact_sh[o_m] = logf(1.0f / (1.0f + expf(-x)));
            }
            __syncthreads();                           // B2

            // ---- e-step: all 1024, role (n,o) ----
            const float4* dmu4 = (const float4*)&dmu_sh[o][0];
            const float4* qq4 = (const float4*)&q_sh[o][0];
            const int row = (n << 4) | o;
            const int swz8 = o & 7;
            float acc2 = 0.0f;
            #pragma unroll
            for (int kc = 0; kc < 8; ++kc) {
                const uint4 w = *(const uint4*)(dvb + row * 128 + ((kc ^ swz8) * 16));
                const float4 mm0 = dmu4[kc * 2], mm1 = dmu4[kc * 2 + 1];
                const float4 q0 = qq4[kc * 2], q1 = qq4[kc * 2 + 1];
                float d;
                d = __uint_as_float(w.x << 16) - mm0.x;         acc2 = fmaf(d * d, q0.x, acc2);
                d = __uint_as_float(w.x & 0xFFFF0000u) - mm0.y; acc2 = fmaf(d * d, q0.y, acc2);
                d = __uint_as_float(w.y << 16) - mm0.z;         acc2 = fmaf(d * d, q0.z, acc2);
                d = __uint_as_float(w.y & 0xFFFF0000u) - mm0.w; acc2 = fmaf(d * d, q0.w, acc2);
                d = __uint_as_float(w.z << 16) - mm1.x;         acc2 = fmaf(d * d, q1.x, acc2);
                d = __uint_as_float(w.z & 0xFFFF0000u) - mm1.y; acc2 = fmaf(d * d, q1.y, acc2);
                d = __uint_as_float(w.w << 16) - mm1.z;         acc2 = fmaf(d * d, q1.z, acc2);
                d = __uint_as_float(w.w & 0xFFFF0000u) - mm1.w; acc2 = fmaf(d * d, q1.w, acc2);
            }
            float la = -acc2 - sumhl_sh[o] - SUM_LN2PI + logact_sh[o];
            if (msk) la = -10000.0f;
            float mx = la;
            mx = fmaxf(mx, __shfl_xor(mx, 1, 64));
            mx = fmaxf(mx, __shfl_xor(mx, 2, 64));
            mx = fmaxf(mx, __shfl_xor(mx, 4, 64));
            mx = fmaxf(mx, __shfl_xor(mx, 8, 64));
            const float ex = __expf(la - mx);
            float se = ex;
            se += __shfl_xor(se, 1, 64);
            se += __shfl_xor(se, 2, 64);
            se += __shfl_xor(se, 4, 64);
            se += __shfl_xor(se, 8, 64);
            r_loc = ex / se;
        } else {
            // ---- final m-step: mu only (same wave layout) ----
            float S10 = 0.0f, S11 = 0.0f, S12 = 0.0f, S13 = 0.0f;
            float A = 0.0f;
            #pragma unroll
            for (int g = 0; g < 4; ++g) {
                const float4 ag = ar4[g];
                #pragma unroll
                for (int i2 = 0; i2 < 4; ++i2) {
                    const float av = (i2 == 0) ? ag.x : (i2 == 1) ? ag.y
                                   : (i2 == 2) ? ag.z : ag.w;
                    const uint2 w2 = *(const uint2*)(dvp + (g * 4 + i2) * 2048);
                    A += av;
                    S10 = fmaf(av, __uint_as_float(w2.x << 16), S10);
                    S11 = fmaf(av, __uint_as_float(w2.x & 0xFFFF0000u), S11);
                    S12 = fmaf(av, __uint_as_float(w2.y << 16), S12);
                    S13 = fmaf(av, __uint_as_float(w2.y & 0xFFFF0000u), S13);
                }
            }
            S10 += __shfl_xor(S10, 16, 64); S10 += __shfl_xor(S10, 32, 64);
            S11 += __shfl_xor(S11, 16, 64); S11 += __shfl_xor(S11, 32, 64);
            S12 += __shfl_xor(S12, 16, 64); S12 += __shfl_xor(S12, 32, 64);
            S13 += __shfl_xor(S13, 16, 64); S13 += __shfl_xor(S13, 32, 64);
            A   += __shfl_xor(A, 16, 64);   A   += __shfl_xor(A, 32, 64);
            const float iD = 1.0f / (A + EPSF);
            if (qn == 0) {
                const float4 outv = make_float4(
                    vbar_sh[e0m + 0] + S10 * iD,
                    vbar_sh[e0m + 1] + S11 * iD,
                    vbar_sh[e0m + 2] + S12 * iD,
                    vbar_sh[e0m + 3] + S13 * iD);
                *(float4*)&out_mu[bl * 1024 + o_m * EE + e0m] = outv;
            }
        }
    }

    out_r[bl * 1024 + tid] = r_loc;    // tid == n*16+o
}

// ---------------------------------------------------------------------------
extern "C" void kernel_launch(void* const* d_in, const int* in_sizes, int n_in,
                              void* d_out, int out_size, void* d_ws, size_t ws_size,
                              hipStream_t stream) {
    const float* inu            = (const float*)d_in[0];
    const unsigned char* mask   = (const unsigned char*)d_in[1];
    const float* ctx            = (const float*)d_in[2];
    const float* rw             = (const float*)d_in[3];
    const float* Wu             = (const float*)d_in[4];
    const float* bu             = (const float*)d_in[5];
    const float* Wc             = (const float*)d_in[6];
    const float* bc             = (const float*)d_in[7];
    const float* Wv             = (const float*)d_in[8];
    const float* bv             = (const float*)d_in[9];
    const float* Wa             = (const float*)d_in[10];
    const float* ba             = (const float*)d_in[11];
    const float* beta_u         = (const float*)d_in[12];
    const float* beta_a         = (const float*)d_in[13];

    _Float16* scwv = (_Float16*)d_ws;                         // 2 MB
    _Float16* u16  = scwv + (size_t)BB * LL * EE * EE;        // 1 MB
    float* vbar_ws = (float*)(u16 + (size_t)BB * 1024 * EE);  // 64 KB
    float* a_ws    = vbar_ws + (size_t)BB * LL * EE;          // 2 KB

    float* out_mu = (float*)d_out;
    float* out_r  = out_mu + (size_t)BB * LL * NOUTV * EE;

    pre_kernel<<<NINV * NOUTV + BB * LL + BB, 256, 0, stream>>>(
        inu, rw, Wu, bu, ctx, Wc, bc, Wv, bv, Wa, ba,
        u16, scwv, vbar_ws, a_ws);
    em_fused_kernel<<<BB * LL, 1024, 0, stream>>>(u16, scwv, vbar_ws, a_ws, mask,
                                                  beta_u, beta_a, out_mu, out_r);
}